// Round 7
// baseline (400.617 us; speedup 1.0000x reference)
//
#include <hip/hip_runtime.h>
#include <math.h>

// Problem constants (match reference)
constexpr int CH         = 64;
constexpr int N_USERS    = 50000;
constexpr int N_ENTITIES = 100000;
constexpr int N_FACTORS  = 4;
constexpr int N_RELM1    = 8;     // N_REL - 1
constexpr int N_EDGES    = 1500000;
constexpr int NNZ        = 800000;

constexpr int NBE        = (N_ENTITIES + 255) / 256;  // 391 coarse buckets (E)
constexpr int NBU        = (N_USERS + 255) / 256;     // 196 coarse buckets (U)
constexpr int NBKT       = NBE + NBU;                 // 587
constexpr int TOTAL      = N_EDGES + NNZ;             // 2.3M items
constexpr int IPB        = 8192;                      // items per count/stage block
constexpr int NBLK       = (TOTAL + IPB - 1) / IPB;   // 281
constexpr int ENT_BLK8   = N_ENTITIES / 8;            // 12500 (exact) — 8 rows/block
constexpr int USR_BLK8   = N_USERS / 8;               // 6250 (exact)

typedef unsigned int u32;
typedef float __attribute__((ext_vector_type(4))) f32x4;

// ---------------------------------------------------------------------------
__device__ __forceinline__ u32 pack_bf16x2(float a, float b) {
    u32 ua = __float_as_uint(a), ub = __float_as_uint(b);
    u32 ra = (ua + 0x7FFFu + ((ua >> 16) & 1u)) >> 16;
    u32 rb = (ub + 0x7FFFu + ((ub >> 16) & 1u)) >> 16;
    return ra | (rb << 16);
}
__device__ __forceinline__ float bf_lo(u32 v) { return __uint_as_float(v << 16); }
__device__ __forceinline__ float bf_hi(u32 v) { return __uint_as_float(v & 0xFFFF0000u); }

// Non-temporal helpers: one-shot streams must NOT allocate in L2/L3 — the
// random-gather table needs that capacity (R4 vs R5 A/B: 175 vs 315 MB/hop).
__device__ __forceinline__ float4 nt_ld4f(const float4* p) {
    f32x4 v = __builtin_nontemporal_load((const f32x4*)p);
    return make_float4(v.x, v.y, v.z, v.w);
}
__device__ __forceinline__ void nt_st4f(float4* p, float4 v) {
    f32x4 t; t.x = v.x; t.y = v.y; t.z = v.z; t.w = v.w;
    __builtin_nontemporal_store(t, (f32x4*)p);
}
__device__ __forceinline__ int   nt_ldi(const int* p)   { return __builtin_nontemporal_load(p); }
__device__ __forceinline__ float nt_ldf(const float* p) { return __builtin_nontemporal_load(p); }

// Exec-masked 16B row-slice gather: returns 0 when invalid (no request issued).
__device__ __forceinline__ uint4 gz(const u32* __restrict__ t, int r, int c8, bool v) {
    uint4 x = make_uint4(0u, 0u, 0u, 0u);
    if (v) x = ((const uint4*)t)[r * 8 + c8];
    return x;
}

__device__ __forceinline__ int coarse_bucket(int i, const int* __restrict__ head,
                                             const int* __restrict__ irows) {
    return (i < N_EDGES) ? (head[i] >> 8) : (NBE + (irows[i - N_EDGES] >> 8));
}

// ---------------------------------------------------------------------------
// A: per-block coarse-bucket histogram -> H[bucket * NBLK + block].
__global__ __launch_bounds__(256)
void count_coarse(const int* __restrict__ head, const int* __restrict__ irows,
                  int* __restrict__ H) {
    __shared__ int hist[NBKT];
    for (int j = threadIdx.x; j < NBKT; j += 256) hist[j] = 0;
    __syncthreads();
    int start = blockIdx.x * IPB;
    int end   = min(start + IPB, TOTAL);
    for (int i = start + threadIdx.x; i < end; i += 256)
        atomicAdd(&hist[coarse_bucket(i, head, irows)], 1);
    __syncthreads();
    for (int j = threadIdx.x; j < NBKT; j += 256)
        H[j * NBLK + blockIdx.x] = hist[j];
}

// B1: one wave per bucket — exclusive scan of H[bucket][0..NBLK), total -> T.
__global__ __launch_bounds__(64)
void scan_hcols(int* __restrict__ H, int* __restrict__ T) {
    int b = blockIdx.x, lane = threadIdx.x;
    int carry = 0;
    #pragma unroll
    for (int c = 0; c < (NBLK + 63) / 64; ++c) {
        int idx = c * 64 + lane;
        int v = (idx < NBLK) ? H[b * NBLK + idx] : 0;
        int incl = v;
        #pragma unroll
        for (int d = 1; d < 64; d <<= 1) {
            int u = __shfl_up(incl, d, 64);
            if (lane >= d) incl += u;
        }
        if (idx < NBLK) H[b * NBLK + idx] = carry + incl - v;
        carry += __shfl(incl, 63, 64);
    }
    if (lane == 0) T[b] = carry;
}

// B2: single block — exclusive scan of T -> Bb, sentinel Bb[NBKT].
__global__ __launch_bounds__(1024)
void scan_buckets(const int* __restrict__ T, int* __restrict__ Bb) {
    __shared__ int lds[1024];
    int t = threadIdx.x;
    int v = (t < NBKT) ? T[t] : 0;
    lds[t] = v;
    __syncthreads();
    for (int d = 1; d < 1024; d <<= 1) {
        int u = (t >= d) ? lds[t - d] : 0;
        __syncthreads();
        lds[t] += u;
        __syncthreads();
    }
    if (t < NBKT) Bb[t] = lds[t] - v;
    if (t == NBKT - 1) Bb[NBKT] = lds[t];
}

// ---------------------------------------------------------------------------
// C: partition into coarse buckets; per-block ranges pre-reserved, LDS atomics.
__global__ __launch_bounds__(256)
void scatter_stage(const int* __restrict__ head, const int* __restrict__ tail,
                   const int* __restrict__ etype,
                   const int* __restrict__ irows, const int* __restrict__ icols,
                   const float* __restrict__ ivals,
                   const int* __restrict__ H, const int* __restrict__ Bb,
                   int2* __restrict__ stageE, int2* __restrict__ stageU,
                   float* __restrict__ stageUv) {
    __shared__ int cur[NBKT];
    for (int j = threadIdx.x; j < NBKT; j += 256)
        cur[j] = Bb[j] + H[j * NBLK + blockIdx.x];
    __syncthreads();
    int start = blockIdx.x * IPB;
    int end   = min(start + IPB, TOTAL);
    for (int i = start + threadIdx.x; i < end; i += 256) {
        if (i < N_EDGES) {
            int k   = head[i];
            int pay = tail[i] | ((etype[i] - 1) << 20);
            int pos = atomicAdd(&cur[k >> 8], 1);
            stageE[pos] = make_int2(k, pay);
        } else {
            int ii  = i - N_EDGES;
            int k   = irows[ii];
            int pos = atomicAdd(&cur[NBE + (k >> 8)], 1) - N_EDGES;
            stageU[pos]  = make_int2(k, icols[ii]);
            stageUv[pos] = ivals[ii];
        }
    }
}

// ---------------------------------------------------------------------------
// D: one block per bucket; LDS key-hist + scan -> CSR offsets, scatter to CSR.
__global__ __launch_bounds__(256)
void bin_fill(const int* __restrict__ Bb,
              const int2* __restrict__ stageE, const int2* __restrict__ stageU,
              const float* __restrict__ stageUv,
              int* __restrict__ offE, int* __restrict__ offU,
              int* __restrict__ elst, int* __restrict__ ucol,
              float* __restrict__ uval) {
    __shared__ int khist[256];
    __shared__ int cur[256];
    int b = blockIdx.x, t = threadIdx.x;
    khist[t] = 0;
    __syncthreads();
    if (b < NBE) {
        int lo = Bb[b], hi = Bb[b + 1];
        for (int i = lo + t; i < hi; i += 256)
            atomicAdd(&khist[stageE[i].x & 255], 1);
        __syncthreads();
        int v = khist[t];
        for (int d = 1; d < 256; d <<= 1) {
            int u = (t >= d) ? khist[t - d] : 0;
            __syncthreads();
            khist[t] += u;
            __syncthreads();
        }
        int excl = lo + khist[t] - v;
        int key  = b * 256 + t;
        if (key < N_ENTITIES) offE[key] = excl;
        cur[t] = excl;
        __syncthreads();
        for (int i = lo + t; i < hi; i += 256) {
            int2 s = stageE[i];
            int p = atomicAdd(&cur[s.x & 255], 1);
            elst[p] = s.y;
        }
        if (b == 0 && t == 0) offE[N_ENTITIES] = N_EDGES;
    } else {
        int lo = Bb[b] - N_EDGES, hi = Bb[b + 1] - N_EDGES;
        for (int i = lo + t; i < hi; i += 256)
            atomicAdd(&khist[stageU[i].x & 255], 1);
        __syncthreads();
        int v = khist[t];
        for (int d = 1; d < 256; d <<= 1) {
            int u = (t >= d) ? khist[t - d] : 0;
            __syncthreads();
            khist[t] += u;
            __syncthreads();
        }
        int excl = lo + khist[t] - v;
        int key  = (b - NBE) * 256 + t;
        if (key < N_USERS) offU[key] = excl;
        cur[t] = excl;
        __syncthreads();
        for (int i = lo + t; i < hi; i += 256) {
            int2 s = stageU[i];
            float vv = stageUv[i];
            int p = atomicAdd(&cur[s.x & 255], 1);
            ucol[p] = s.y;
            uval[p] = vv;
        }
        if (b == NBE && t == 0) offU[N_USERS] = NNZ;
    }
}

// ---------------------------------------------------------------------------
// Convert fp32 table -> packed bf16x2 (u32 per channel pair).
__global__ __launch_bounds__(256)
void to_bf16(const float* __restrict__ src, u32* __restrict__ dst, int n2) {
    int i = blockIdx.x * 256 + threadIdx.x;
    if (i < n2) {
        float2 f = ((const float2*)src)[i];
        dst[i] = pack_bf16x2(f.x, f.y);
    }
}

// ---------------------------------------------------------------------------
// Fused per-hop pass, bf16 gather table.
// Wave = 2 rows (h = lane>>5). Within a half: g = (lane>>3)&3 (4 gather groups
// of 8), c8 = lane&7 (channel octet -> one uint4 = 128b row slice per gather).
// Per 32-edge chunk: ONE coalesced 32-lane index load, then __shfl(p,j,32)
// register broadcasts feed the gathers — no memory op on the index path.
// Cache policy (R4/R5 A/B-tested): all one-shot streams nt (loads+stores);
// ONLY table gathers allocate — except AeB (hop1's gather table), stored
// cached so hop1 starts warm. LB(256,8): 8 waves/SIMD to hide L3 latency.
__device__ __forceinline__ void acc_edge(float* acc, uint4 xv, float4 wa, float4 wb) {
    acc[0] += bf_lo(xv.x) * wa.x; acc[1] += bf_hi(xv.x) * wa.y;
    acc[2] += bf_lo(xv.y) * wa.z; acc[3] += bf_hi(xv.y) * wa.w;
    acc[4] += bf_lo(xv.z) * wb.x; acc[5] += bf_hi(xv.z) * wb.y;
    acc[6] += bf_lo(xv.w) * wb.z; acc[7] += bf_hi(xv.w) * wb.w;
}
__device__ __forceinline__ void acc_user(float* acc, uint4 xv, float vv) {
    acc[0] += vv * bf_lo(xv.x); acc[1] += vv * bf_hi(xv.x);
    acc[2] += vv * bf_lo(xv.y); acc[3] += vv * bf_hi(xv.y);
    acc[4] += vv * bf_lo(xv.z); acc[5] += vv * bf_hi(xv.z);
    acc[6] += vv * bf_lo(xv.w); acc[7] += vv * bf_hi(xv.w);
}

template <bool HOP0>
__global__ __launch_bounds__(256, 8)
void hop_pass(const u32* __restrict__ entB,       // bf16x2 entity table (gathered)
              const float* __restrict__ usr_in,   // fp32 user emb (dense)
              const float* __restrict__ weight, const float* __restrict__ latent,
              const float* __restrict__ dw,
              const int* __restrict__ offE, const int* __restrict__ elst,
              const int* __restrict__ offU, const int* __restrict__ ucol,
              const float* __restrict__ uval,
              u32* __restrict__ AeB_out,          // bf16x2 entity out (hop0)
              float* __restrict__ Au_out,         // fp32 user out (hop0)
              float* __restrict__ ent_res, float* __restrict__ usr_res,
              const float* __restrict__ ent_base, const float* __restrict__ usr_base) {
    __shared__ float4 w4[N_RELM1 * 16];           // weight as float4 rows (2KB)
    int lane = threadIdx.x & 63;
    int h    = lane >> 5;          // row of the pair
    int g    = (lane >> 3) & 3;    // gather group within half
    int c8   = lane & 7;           // channel octet
    int l5   = lane & 31;
    float acc[8] = {0.f, 0.f, 0.f, 0.f, 0.f, 0.f, 0.f, 0.f};

    if ((int)blockIdx.x < ENT_BLK8) {
        if (threadIdx.x < N_RELM1 * 16)
            w4[threadIdx.x] = ((const float4*)weight)[threadIdx.x];
        __syncthreads();
        int row = blockIdx.x * 8 + ((threadIdx.x >> 6) << 1) + h;
        int lo = offE[row], hi = offE[row + 1];
        for (int k0 = lo; k0 < hi; k0 += 32) {
            int m = min(32, hi - k0);                       // uniform per half
            int p = nt_ldi(&elst[min(k0 + l5, N_EDGES - 1)]);
            for (int jj = 0; jj < m; jj += 16) {
                int j0 = jj + g;
                int q0 = __shfl(p, j0,      32);
                int q1 = __shfl(p, j0 + 4,  32);
                int q2 = __shfl(p, j0 + 8,  32);
                int q3 = __shfl(p, j0 + 12, 32);
                uint4 x0 = gz(entB, q0 & 0xFFFFF, c8, j0      < m);
                uint4 x1 = gz(entB, q1 & 0xFFFFF, c8, j0 + 4  < m);
                uint4 x2 = gz(entB, q2 & 0xFFFFF, c8, j0 + 8  < m);
                uint4 x3 = gz(entB, q3 & 0xFFFFF, c8, j0 + 12 < m);
                float4 wa0 = w4[(q0 >> 20) * 16 + (c8 << 1)];
                float4 wb0 = w4[(q0 >> 20) * 16 + (c8 << 1) + 1];
                float4 wa1 = w4[(q1 >> 20) * 16 + (c8 << 1)];
                float4 wb1 = w4[(q1 >> 20) * 16 + (c8 << 1) + 1];
                float4 wa2 = w4[(q2 >> 20) * 16 + (c8 << 1)];
                float4 wb2 = w4[(q2 >> 20) * 16 + (c8 << 1) + 1];
                float4 wa3 = w4[(q3 >> 20) * 16 + (c8 << 1)];
                float4 wb3 = w4[(q3 >> 20) * 16 + (c8 << 1) + 1];
                acc_edge(acc, x0, wa0, wb0);
                acc_edge(acc, x1, wa1, wb1);
                acc_edge(acc, x2, wa2, wb2);
                acc_edge(acc, x3, wa3, wb3);
            }
        }
        #pragma unroll
        for (int j = 0; j < 8; ++j) {            // combine 4 groups (within half)
            acc[j] += __shfl_xor(acc[j], 8, 64);
            acc[j] += __shfl_xor(acc[j], 16, 64);
        }
        float s = 0.0f;
        #pragma unroll
        for (int j = 0; j < 8; ++j) s += acc[j] * acc[j];
        s += __shfl_xor(s, 1, 64);
        s += __shfl_xor(s, 2, 64);
        s += __shfl_xor(s, 4, 64);
        float inv = 1.0f / fmaxf(sqrtf(s), 1e-12f);
        if (g == 0) {
            float y0 = acc[0] * inv, y1 = acc[1] * inv, y2 = acc[2] * inv, y3 = acc[3] * inv;
            float y4 = acc[4] * inv, y5 = acc[5] * inv, y6 = acc[6] * inv, y7 = acc[7] * inv;
            int qi = row * 16 + (c8 << 1);
            if (HOP0) {
                uint4 pk;
                pk.x = pack_bf16x2(y0, y1); pk.y = pack_bf16x2(y2, y3);
                pk.z = pack_bf16x2(y4, y5); pk.w = pack_bf16x2(y6, y7);
                ((uint4*)AeB_out)[row * 8 + c8] = pk;   // hop1's gather table: cached
                float4 b0 = nt_ld4f(&((const float4*)ent_base)[qi]);
                float4 b1 = nt_ld4f(&((const float4*)ent_base)[qi + 1]);
                nt_st4f(&((float4*)ent_res)[qi],     make_float4(b0.x + y0, b0.y + y1, b0.z + y2, b0.w + y3));
                nt_st4f(&((float4*)ent_res)[qi + 1], make_float4(b1.x + y4, b1.y + y5, b1.z + y6, b1.w + y7));
            } else {
                float4 r0 = nt_ld4f(&((const float4*)ent_res)[qi]);
                float4 r1 = nt_ld4f(&((const float4*)ent_res)[qi + 1]);
                nt_st4f(&((float4*)ent_res)[qi],     make_float4(r0.x + y0, r0.y + y1, r0.z + y2, r0.w + y3));
                nt_st4f(&((float4*)ent_res)[qi + 1], make_float4(r1.x + y4, r1.y + y5, r1.z + y6, r1.w + y7));
            }
        }
    } else {
        int row = (blockIdx.x - ENT_BLK8) * 8 + ((threadIdx.x >> 6) << 1) + h;
        int qi  = row * 16 + (c8 << 1);
        float4 u0 = nt_ld4f(&((const float4*)usr_in)[qi]);    // prefetch; used post-loop
        float4 u1 = nt_ld4f(&((const float4*)usr_in)[qi + 1]);
        int lo = offU[row], hi = offU[row + 1];
        for (int k0 = lo; k0 < hi; k0 += 32) {
            int m = min(32, hi - k0);
            int sidx = min(k0 + l5, NNZ - 1);
            int   cl = nt_ldi(&ucol[sidx]);
            float vl = nt_ldf(&uval[sidx]);
            for (int jj = 0; jj < m; jj += 16) {
                int j0 = jj + g;
                int   c0 = __shfl(cl, j0,      32);
                int   c1 = __shfl(cl, j0 + 4,  32);
                int   c2 = __shfl(cl, j0 + 8,  32);
                int   c3 = __shfl(cl, j0 + 12, 32);
                float v0 = __shfl(vl, j0,      32);
                float v1 = __shfl(vl, j0 + 4,  32);
                float v2 = __shfl(vl, j0 + 8,  32);
                float v3 = __shfl(vl, j0 + 12, 32);
                uint4 x0 = gz(entB, c0, c8, j0      < m);
                uint4 x1 = gz(entB, c1, c8, j0 + 4  < m);
                uint4 x2 = gz(entB, c2, c8, j0 + 8  < m);
                uint4 x3 = gz(entB, c3, c8, j0 + 12 < m);
                acc_user(acc, x0, v0);
                acc_user(acc, x1, v1);
                acc_user(acc, x2, v2);
                acc_user(acc, x3, v3);
            }
        }
        #pragma unroll
        for (int j = 0; j < 8; ++j) {
            acc[j] += __shfl_xor(acc[j], 8, 64);
            acc[j] += __shfl_xor(acc[j], 16, 64);
        }
        // softmax(u @ latent^T) @ dw — computed after the gather loop so the
        // usr_in loads prefetch under it.
        float d[N_FACTORS];
        #pragma unroll
        for (int f = 0; f < N_FACTORS; ++f) {
            float4 l0 = ((const float4*)latent)[f * 16 + (c8 << 1)];
            float4 l1 = ((const float4*)latent)[f * 16 + (c8 << 1) + 1];
            d[f] = u0.x * l0.x + u0.y * l0.y + u0.z * l0.z + u0.w * l0.w
                 + u1.x * l1.x + u1.y * l1.y + u1.z * l1.z + u1.w * l1.w;
            d[f] += __shfl_xor(d[f], 1, 64);
            d[f] += __shfl_xor(d[f], 2, 64);
            d[f] += __shfl_xor(d[f], 4, 64);
        }
        float mx = fmaxf(fmaxf(d[0], d[1]), fmaxf(d[2], d[3]));
        float ex0 = expf(d[0] - mx), ex1 = expf(d[1] - mx);
        float ex2 = expf(d[2] - mx), ex3 = expf(d[3] - mx);
        float sinv = 1.0f / (ex0 + ex1 + ex2 + ex3);
        float mix[8] = {0.f, 0.f, 0.f, 0.f, 0.f, 0.f, 0.f, 0.f};
        {
            float exf[N_FACTORS] = {ex0, ex1, ex2, ex3};
            #pragma unroll
            for (int f = 0; f < N_FACTORS; ++f) {
                float4 w0 = ((const float4*)dw)[f * 16 + (c8 << 1)];
                float4 w1 = ((const float4*)dw)[f * 16 + (c8 << 1) + 1];
                float ef = exf[f];
                mix[0] += ef * w0.x; mix[1] += ef * w0.y;
                mix[2] += ef * w0.z; mix[3] += ef * w0.w;
                mix[4] += ef * w1.x; mix[5] += ef * w1.y;
                mix[6] += ef * w1.z; mix[7] += ef * w1.w;
            }
            #pragma unroll
            for (int j = 0; j < 8; ++j) mix[j] *= sinv;
        }
        float un[8];
        #pragma unroll
        for (int j = 0; j < 8; ++j) un[j] = acc[j] * (1.0f + mix[j]);
        float s = 0.0f;
        #pragma unroll
        for (int j = 0; j < 8; ++j) s += un[j] * un[j];
        s += __shfl_xor(s, 1, 64);
        s += __shfl_xor(s, 2, 64);
        s += __shfl_xor(s, 4, 64);
        float inv = 1.0f / fmaxf(sqrtf(s), 1e-12f);
        if (g == 0) {
            float y0 = un[0] * inv, y1 = un[1] * inv, y2 = un[2] * inv, y3 = un[3] * inv;
            float y4 = un[4] * inv, y5 = un[5] * inv, y6 = un[6] * inv, y7 = un[7] * inv;
            if (HOP0) {
                nt_st4f(&((float4*)Au_out)[qi],     make_float4(y0, y1, y2, y3));
                nt_st4f(&((float4*)Au_out)[qi + 1], make_float4(y4, y5, y6, y7));
                float4 b0 = nt_ld4f(&((const float4*)usr_base)[qi]);
                float4 b1 = nt_ld4f(&((const float4*)usr_base)[qi + 1]);
                nt_st4f(&((float4*)usr_res)[qi],     make_float4(b0.x + y0, b0.y + y1, b0.z + y2, b0.w + y3));
                nt_st4f(&((float4*)usr_res)[qi + 1], make_float4(b1.x + y4, b1.y + y5, b1.z + y6, b1.w + y7));
            } else {
                float4 r0 = nt_ld4f(&((const float4*)usr_res)[qi]);
                float4 r1 = nt_ld4f(&((const float4*)usr_res)[qi + 1]);
                nt_st4f(&((float4*)usr_res)[qi],     make_float4(r0.x + y0, r0.y + y1, r0.z + y2, r0.w + y3));
                nt_st4f(&((float4*)usr_res)[qi + 1], make_float4(r1.x + y4, r1.y + y5, r1.z + y6, r1.w + y7));
            }
        }
    }
}

// ---------------------------------------------------------------------------
// Block 0: disen_weight = softmax(att,-1) @ weight (4x8 @ 8x64).
// Block 1: distance-correlation, one wave per factor pair.
__global__ __launch_bounds__(384)
void discor_kernel(const float* __restrict__ att,
                   const float* __restrict__ weight,
                   float* __restrict__ dw,
                   float* __restrict__ cor_out) {
    __shared__ float part[6];
    if (blockIdx.x == 0) {
        if (threadIdx.x < 256) {
            int f = threadIdx.x >> 6;
            int c = threadIdx.x & 63;
            float m = -1e30f;
            #pragma unroll
            for (int j = 0; j < N_RELM1; ++j) m = fmaxf(m, att[f * N_RELM1 + j]);
            float s = 0.0f, w[N_RELM1];
            #pragma unroll
            for (int j = 0; j < N_RELM1; ++j) { w[j] = expf(att[f * N_RELM1 + j] - m); s += w[j]; }
            float acc = 0.0f;
            #pragma unroll
            for (int j = 0; j < N_RELM1; ++j) acc += w[j] * weight[j * CH + c];
            dw[f * CH + c] = acc / s;
        }
    } else {
        int w    = threadIdx.x >> 6;   // 0..5 = pair index
        int lane = threadIdx.x & 63;
        const int pi[6] = {0, 0, 0, 1, 1, 2};
        const int pj[6] = {1, 2, 3, 2, 3, 3};
        int r = lane >> 3, c = lane & 7;
        const float* t1 = att + pi[w] * N_RELM1;
        const float* t2 = att + pj[w] * N_RELM1;
        float a  = sqrtf(fmaxf(t1[r] * t1[r] - 2.0f * t1[r] * t1[c] + t1[c] * t1[c], 0.0f) + 1e-8f);
        float bb = sqrtf(fmaxf(t2[r] * t2[r] - 2.0f * t2[r] * t2[c] + t2[c] * t2[c], 0.0f) + 1e-8f);
        float rsA = a, rsB = bb;
        #pragma unroll
        for (int o = 1; o < 8; o <<= 1) { rsA += __shfl_xor(rsA, o, 64); rsB += __shfl_xor(rsB, o, 64); }
        float csA = a, csB = bb;
        #pragma unroll
        for (int o = 8; o < 64; o <<= 1) { csA += __shfl_xor(csA, o, 64); csB += __shfl_xor(csB, o, 64); }
        float totA = rsA, totB = rsB;
        #pragma unroll
        for (int o = 8; o < 64; o <<= 1) { totA += __shfl_xor(totA, o, 64); totB += __shfl_xor(totB, o, 64); }
        float A = a  - csA * 0.125f - rsA * 0.125f + totA * (1.0f / 64.0f);
        float B = bb - csB * 0.125f - rsB * 0.125f + totB * (1.0f / 64.0f);
        float sAB = A * B, sAA = A * A, sBB = B * B;
        #pragma unroll
        for (int o = 1; o < 64; o <<= 1) {
            sAB += __shfl_xor(sAB, o, 64);
            sAA += __shfl_xor(sAA, o, 64);
            sBB += __shfl_xor(sBB, o, 64);
        }
        if (lane == 0) {
            float dAB = sqrtf(fmaxf(sAB * (1.0f / 64.0f), 0.0f) + 1e-8f);
            float dAA = sqrtf(fmaxf(sAA * (1.0f / 64.0f), 0.0f) + 1e-8f);
            float dBB = sqrtf(fmaxf(sBB * (1.0f / 64.0f), 0.0f) + 1e-8f);
            part[w] = dAB / sqrtf(dAA * dBB + 1e-8f);
        }
        __syncthreads();
        if (threadIdx.x == 0) {
            float s = 0.0f;
            for (int q = 0; q < 6; ++q) s += part[q];
            cor_out[0] = s;
        }
    }
}

// ---------------------------------------------------------------------------
extern "C" void kernel_launch(void* const* d_in, const int* in_sizes, int n_in,
                              void* d_out, int out_size, void* d_ws, size_t ws_size,
                              hipStream_t stream) {
    const float* user_emb   = (const float*)d_in[0];
    const float* entity_emb = (const float*)d_in[1];
    const float* latent     = (const float*)d_in[2];
    const float* weight     = (const float*)d_in[3];
    const float* att        = (const float*)d_in[4];
    const float* ivals      = (const float*)d_in[5];
    const int*   head       = (const int*)d_in[6];
    const int*   tail       = (const int*)d_in[7];
    const int*   etype      = (const int*)d_in[8];
    const int*   irows      = (const int*)d_in[9];
    const int*   icols      = (const int*)d_in[10];

    float* out     = (float*)d_out;
    float* ent_res = out;
    float* usr_res = out + (size_t)N_ENTITIES * CH;
    float* cor_out = out + (size_t)N_ENTITIES * CH + (size_t)N_USERS * CH;

    const size_t ENT_ELEMS = (size_t)N_ENTITIES * CH;   // 6.4M
    const size_t USR_ELEMS = (size_t)N_USERS * CH;      // 3.2M
    const int    ENT_PAIRS = (int)(ENT_ELEMS / 2);      // 3.2M u32

    // Workspace carve-up (~52 MB).
    // Region R: [entB | AeB] (25.6 MB) — aliased by the CSR staging arrays
    // (21.6 MB), which are dead before to_bf16/hop0 write entB/AeB.
    float* ws   = (float*)d_ws;
    u32*   entB = (u32*)ws;                         // 3.2M u32 (12.8 MB)
    u32*   AeB  = entB + ENT_PAIRS;                 // 3.2M u32 (12.8 MB)
    float* Au   = (float*)(AeB + ENT_PAIRS);        // 3.2M f32 (12.8 MB)
    float* dw   = Au + USR_ELEMS;                   // 4x64
    int*   offE = (int*)(dw + N_FACTORS * CH);      // 100001
    int*   offU = offE + N_ENTITIES + 1;            // 50001
    int*   elst = offU + N_USERS + 1;               // 1.5M packed
    int*   ucol = elst + N_EDGES;                   // 800K
    float* uval = (float*)(ucol + NNZ);             // 800K
    int*   H    = (int*)(uval + NNZ);               // NBKT*NBLK = 164947
    int*   T    = H + NBKT * NBLK;                  // 587
    int*   Bb   = T + NBKT;                         // 588
    // Staging aliased on R: 1.5M int2 + 800K int2 + 800K f32 = 21.6 MB < 25.6 MB
    int2*  stageE  = (int2*)entB;
    int2*  stageU  = ((int2*)entB) + N_EDGES;
    float* stageUv = (float*)(stageU + NNZ);

    discor_kernel<<<2, 384, 0, stream>>>(att, weight, dw, cor_out);

    // ---- Build CSR (no global atomics, no memsets) ----
    count_coarse<<<NBLK, 256, 0, stream>>>(head, irows, H);
    scan_hcols<<<NBKT, 64, 0, stream>>>(H, T);
    scan_buckets<<<1, 1024, 0, stream>>>(T, Bb);
    scatter_stage<<<NBLK, 256, 0, stream>>>(head, tail, etype, irows, icols, ivals,
                                            H, Bb, stageE, stageU, stageUv);
    bin_fill<<<NBKT, 256, 0, stream>>>(Bb, stageE, stageU, stageUv,
                                       offE, offU, elst, ucol, uval);

    // ---- Convert gather table to bf16 (staging now dead) ----
    to_bf16<<<(ENT_PAIRS + 255) / 256, 256, 0, stream>>>(entity_emb, entB, ENT_PAIRS);

    // ---- Hop 0 (gathers entB; writes AeB bf16 + Au fp32 + residuals) ----
    hop_pass<true><<<ENT_BLK8 + USR_BLK8, 256, 0, stream>>>(
        entB, user_emb, weight, latent, dw,
        offE, elst, offU, ucol, uval,
        AeB, Au, ent_res, usr_res, entity_emb, user_emb);

    // ---- Hop 1 (gathers AeB) ----
    hop_pass<false><<<ENT_BLK8 + USR_BLK8, 256, 0, stream>>>(
        AeB, Au, weight, latent, dw,
        offE, elst, offU, ucol, uval,
        nullptr, nullptr, ent_res, usr_res, nullptr, nullptr);
}

// Round 8
// 361.422 us; speedup vs baseline: 1.1084x; 1.1084x over previous
//
#include <hip/hip_runtime.h>
#include <math.h>

// Problem constants (match reference)
constexpr int CH         = 64;
constexpr int N_USERS    = 50000;
constexpr int N_ENTITIES = 100000;
constexpr int N_FACTORS  = 4;
constexpr int N_RELM1    = 8;     // N_REL - 1
constexpr int N_EDGES    = 1500000;
constexpr int NNZ        = 800000;

constexpr int NBE        = (N_ENTITIES + 255) / 256;  // 391 coarse buckets (E)
constexpr int NBU        = (N_USERS + 255) / 256;     // 196 coarse buckets (U)
constexpr int NBKT       = NBE + NBU;                 // 587
constexpr int TOTAL      = N_EDGES + NNZ;             // 2.3M items
constexpr int IPB        = 8192;                      // items per count/stage block
constexpr int NBLK       = (TOTAL + IPB - 1) / IPB;   // 281
constexpr int ENT_BLK8   = N_ENTITIES / 8;            // 12500 (exact) — 8 rows/block
constexpr int USR_BLK8   = N_USERS / 8;               // 6250 (exact)

typedef unsigned int u32;
typedef float __attribute__((ext_vector_type(4))) f32x4;
typedef unsigned int __attribute__((ext_vector_type(4))) u32x4;

// ---------------------------------------------------------------------------
__device__ __forceinline__ u32 pack_bf16x2(float a, float b) {
    u32 ua = __float_as_uint(a), ub = __float_as_uint(b);
    u32 ra = (ua + 0x7FFFu + ((ua >> 16) & 1u)) >> 16;
    u32 rb = (ub + 0x7FFFu + ((ub >> 16) & 1u)) >> 16;
    return ra | (rb << 16);
}
__device__ __forceinline__ float bf_lo(u32 v) { return __uint_as_float(v << 16); }
__device__ __forceinline__ float bf_hi(u32 v) { return __uint_as_float(v & 0xFFFF0000u); }

// Non-temporal helpers: one-shot streams must NOT allocate in L2/L3 — the
// random-gather table needs that capacity. A/B evidence: R4 (all-nt, occ 47%)
// = 81 µs/hop @175 MB; R5/R7 (occ 75%, any policy) = 92-97 µs @315 MB.
__device__ __forceinline__ float4 nt_ld4f(const float4* p) {
    f32x4 v = __builtin_nontemporal_load((const f32x4*)p);
    return make_float4(v.x, v.y, v.z, v.w);
}
__device__ __forceinline__ void nt_st4f(float4* p, float4 v) {
    f32x4 t; t.x = v.x; t.y = v.y; t.z = v.z; t.w = v.w;
    __builtin_nontemporal_store(t, (f32x4*)p);
}
__device__ __forceinline__ void nt_st4u(uint4* p, uint4 v) {
    u32x4 t; t.x = v.x; t.y = v.y; t.z = v.z; t.w = v.w;
    __builtin_nontemporal_store(t, (u32x4*)p);
}
__device__ __forceinline__ int   nt_ldi(const int* p)   { return __builtin_nontemporal_load(p); }
__device__ __forceinline__ float nt_ldf(const float* p) { return __builtin_nontemporal_load(p); }

// Exec-masked 16B row-slice gather: returns 0 when invalid (no request issued).
__device__ __forceinline__ uint4 gz(const u32* __restrict__ t, int r, int c8, bool v) {
    uint4 x = make_uint4(0u, 0u, 0u, 0u);
    if (v) x = ((const uint4*)t)[r * 8 + c8];
    return x;
}

__device__ __forceinline__ int coarse_bucket(int i, const int* __restrict__ head,
                                             const int* __restrict__ irows) {
    return (i < N_EDGES) ? (head[i] >> 8) : (NBE + (irows[i - N_EDGES] >> 8));
}

// ---------------------------------------------------------------------------
// A: per-block coarse-bucket histogram -> H[bucket * NBLK + block].
__global__ __launch_bounds__(256)
void count_coarse(const int* __restrict__ head, const int* __restrict__ irows,
                  int* __restrict__ H) {
    __shared__ int hist[NBKT];
    for (int j = threadIdx.x; j < NBKT; j += 256) hist[j] = 0;
    __syncthreads();
    int start = blockIdx.x * IPB;
    int end   = min(start + IPB, TOTAL);
    for (int i = start + threadIdx.x; i < end; i += 256)
        atomicAdd(&hist[coarse_bucket(i, head, irows)], 1);
    __syncthreads();
    for (int j = threadIdx.x; j < NBKT; j += 256)
        H[j * NBLK + blockIdx.x] = hist[j];
}

// B1: one wave per bucket — exclusive scan of H[bucket][0..NBLK), total -> T.
__global__ __launch_bounds__(64)
void scan_hcols(int* __restrict__ H, int* __restrict__ T) {
    int b = blockIdx.x, lane = threadIdx.x;
    int carry = 0;
    #pragma unroll
    for (int c = 0; c < (NBLK + 63) / 64; ++c) {
        int idx = c * 64 + lane;
        int v = (idx < NBLK) ? H[b * NBLK + idx] : 0;
        int incl = v;
        #pragma unroll
        for (int d = 1; d < 64; d <<= 1) {
            int u = __shfl_up(incl, d, 64);
            if (lane >= d) incl += u;
        }
        if (idx < NBLK) H[b * NBLK + idx] = carry + incl - v;
        carry += __shfl(incl, 63, 64);
    }
    if (lane == 0) T[b] = carry;
}

// B2: single block — exclusive scan of T -> Bb, sentinel Bb[NBKT].
__global__ __launch_bounds__(1024)
void scan_buckets(const int* __restrict__ T, int* __restrict__ Bb) {
    __shared__ int lds[1024];
    int t = threadIdx.x;
    int v = (t < NBKT) ? T[t] : 0;
    lds[t] = v;
    __syncthreads();
    for (int d = 1; d < 1024; d <<= 1) {
        int u = (t >= d) ? lds[t - d] : 0;
        __syncthreads();
        lds[t] += u;
        __syncthreads();
    }
    if (t < NBKT) Bb[t] = lds[t] - v;
    if (t == NBKT - 1) Bb[NBKT] = lds[t];
}

// ---------------------------------------------------------------------------
// C: partition into coarse buckets; per-block ranges pre-reserved, LDS atomics.
__global__ __launch_bounds__(256)
void scatter_stage(const int* __restrict__ head, const int* __restrict__ tail,
                   const int* __restrict__ etype,
                   const int* __restrict__ irows, const int* __restrict__ icols,
                   const float* __restrict__ ivals,
                   const int* __restrict__ H, const int* __restrict__ Bb,
                   int2* __restrict__ stageE, int2* __restrict__ stageU,
                   float* __restrict__ stageUv) {
    __shared__ int cur[NBKT];
    for (int j = threadIdx.x; j < NBKT; j += 256)
        cur[j] = Bb[j] + H[j * NBLK + blockIdx.x];
    __syncthreads();
    int start = blockIdx.x * IPB;
    int end   = min(start + IPB, TOTAL);
    for (int i = start + threadIdx.x; i < end; i += 256) {
        if (i < N_EDGES) {
            int k   = head[i];
            int pay = tail[i] | ((etype[i] - 1) << 20);
            int pos = atomicAdd(&cur[k >> 8], 1);
            stageE[pos] = make_int2(k, pay);
        } else {
            int ii  = i - N_EDGES;
            int k   = irows[ii];
            int pos = atomicAdd(&cur[NBE + (k >> 8)], 1) - N_EDGES;
            stageU[pos]  = make_int2(k, icols[ii]);
            stageUv[pos] = ivals[ii];
        }
    }
}

// ---------------------------------------------------------------------------
// D: one block per bucket; LDS key-hist + scan -> CSR offsets, scatter to CSR.
__global__ __launch_bounds__(256)
void bin_fill(const int* __restrict__ Bb,
              const int2* __restrict__ stageE, const int2* __restrict__ stageU,
              const float* __restrict__ stageUv,
              int* __restrict__ offE, int* __restrict__ offU,
              int* __restrict__ elst, int* __restrict__ ucol,
              float* __restrict__ uval) {
    __shared__ int khist[256];
    __shared__ int cur[256];
    int b = blockIdx.x, t = threadIdx.x;
    khist[t] = 0;
    __syncthreads();
    if (b < NBE) {
        int lo = Bb[b], hi = Bb[b + 1];
        for (int i = lo + t; i < hi; i += 256)
            atomicAdd(&khist[stageE[i].x & 255], 1);
        __syncthreads();
        int v = khist[t];
        for (int d = 1; d < 256; d <<= 1) {
            int u = (t >= d) ? khist[t - d] : 0;
            __syncthreads();
            khist[t] += u;
            __syncthreads();
        }
        int excl = lo + khist[t] - v;
        int key  = b * 256 + t;
        if (key < N_ENTITIES) offE[key] = excl;
        cur[t] = excl;
        __syncthreads();
        for (int i = lo + t; i < hi; i += 256) {
            int2 s = stageE[i];
            int p = atomicAdd(&cur[s.x & 255], 1);
            elst[p] = s.y;
        }
        if (b == 0 && t == 0) offE[N_ENTITIES] = N_EDGES;
    } else {
        int lo = Bb[b] - N_EDGES, hi = Bb[b + 1] - N_EDGES;
        for (int i = lo + t; i < hi; i += 256)
            atomicAdd(&khist[stageU[i].x & 255], 1);
        __syncthreads();
        int v = khist[t];
        for (int d = 1; d < 256; d <<= 1) {
            int u = (t >= d) ? khist[t - d] : 0;
            __syncthreads();
            khist[t] += u;
            __syncthreads();
        }
        int excl = lo + khist[t] - v;
        int key  = (b - NBE) * 256 + t;
        if (key < N_USERS) offU[key] = excl;
        cur[t] = excl;
        __syncthreads();
        for (int i = lo + t; i < hi; i += 256) {
            int2 s = stageU[i];
            float vv = stageUv[i];
            int p = atomicAdd(&cur[s.x & 255], 1);
            ucol[p] = s.y;
            uval[p] = vv;
        }
        if (b == NBE && t == 0) offU[N_USERS] = NNZ;
    }
}

// ---------------------------------------------------------------------------
// Convert fp32 table -> packed bf16x2 (u32 per channel pair).
__global__ __launch_bounds__(256)
void to_bf16(const float* __restrict__ src, u32* __restrict__ dst, int n2) {
    int i = blockIdx.x * 256 + threadIdx.x;
    if (i < n2) {
        float2 f = ((const float2*)src)[i];
        dst[i] = pack_bf16x2(f.x, f.y);
    }
}

// ---------------------------------------------------------------------------
// Fused per-hop pass, bf16 gather table.
// Wave = 2 rows (h = lane>>5). Within a half: g = (lane>>3)&3 (4 gather groups
// of 8), c8 = lane&7 (channel octet -> one uint4 = 128b row slice per gather).
// Per 32-edge chunk: ONE coalesced 32-lane index load, then __shfl(p,j,32)
// register broadcasts feed the gathers — no memory op on the index path.
// Cache policy (R4 proven best, 81 µs/hop): all one-shot streams nt; only
// table gathers allocate. NO min-waves clause — LB(256,8) raised occupancy to
// 75% and REGRESSED (R7: +140 MB L2-miss traffic, 97 µs/hop): the hop is
// L2-miss-path bound; 47% occupancy minimizes table thrash.
// User residual: hop0 writes only Au (= y0, fp32); hop1 computes
// final = usr_base + Au + y1 (bit-identical FP order to the old RMW chain).
__device__ __forceinline__ void acc_edge(float* acc, uint4 xv, float4 wa, float4 wb) {
    acc[0] += bf_lo(xv.x) * wa.x; acc[1] += bf_hi(xv.x) * wa.y;
    acc[2] += bf_lo(xv.y) * wa.z; acc[3] += bf_hi(xv.y) * wa.w;
    acc[4] += bf_lo(xv.z) * wb.x; acc[5] += bf_hi(xv.z) * wb.y;
    acc[6] += bf_lo(xv.w) * wb.z; acc[7] += bf_hi(xv.w) * wb.w;
}
__device__ __forceinline__ void acc_user(float* acc, uint4 xv, float vv) {
    acc[0] += vv * bf_lo(xv.x); acc[1] += vv * bf_hi(xv.x);
    acc[2] += vv * bf_lo(xv.y); acc[3] += vv * bf_hi(xv.y);
    acc[4] += vv * bf_lo(xv.z); acc[5] += vv * bf_hi(xv.z);
    acc[6] += vv * bf_lo(xv.w); acc[7] += vv * bf_hi(xv.w);
}

template <bool HOP0>
__global__ __launch_bounds__(256)
void hop_pass(const u32* __restrict__ entB,       // bf16x2 entity table (gathered)
              const float* __restrict__ usr_in,   // fp32 user emb (dense)
              const float* __restrict__ weight, const float* __restrict__ latent,
              const float* __restrict__ dw,
              const int* __restrict__ offE, const int* __restrict__ elst,
              const int* __restrict__ offU, const int* __restrict__ ucol,
              const float* __restrict__ uval,
              u32* __restrict__ AeB_out,          // bf16x2 entity out (hop0)
              float* __restrict__ Au_out,         // fp32 user out (hop0)
              float* __restrict__ ent_res, float* __restrict__ usr_res,
              const float* __restrict__ ent_base, const float* __restrict__ usr_base) {
    __shared__ float4 w4[N_RELM1 * 16];           // weight as float4 rows (2KB)
    int lane = threadIdx.x & 63;
    int h    = lane >> 5;          // row of the pair
    int g    = (lane >> 3) & 3;    // gather group within half
    int c8   = lane & 7;           // channel octet
    int l5   = lane & 31;
    float acc[8] = {0.f, 0.f, 0.f, 0.f, 0.f, 0.f, 0.f, 0.f};

    if ((int)blockIdx.x < ENT_BLK8) {
        if (threadIdx.x < N_RELM1 * 16)
            w4[threadIdx.x] = ((const float4*)weight)[threadIdx.x];
        __syncthreads();
        int row = blockIdx.x * 8 + ((threadIdx.x >> 6) << 1) + h;
        int lo = offE[row], hi = offE[row + 1];
        for (int k0 = lo; k0 < hi; k0 += 32) {
            int m = min(32, hi - k0);                       // uniform per half
            int p = nt_ldi(&elst[min(k0 + l5, N_EDGES - 1)]);
            for (int jj = 0; jj < m; jj += 16) {
                int j0 = jj + g;
                int q0 = __shfl(p, j0,      32);
                int q1 = __shfl(p, j0 + 4,  32);
                int q2 = __shfl(p, j0 + 8,  32);
                int q3 = __shfl(p, j0 + 12, 32);
                uint4 x0 = gz(entB, q0 & 0xFFFFF, c8, j0      < m);
                uint4 x1 = gz(entB, q1 & 0xFFFFF, c8, j0 + 4  < m);
                uint4 x2 = gz(entB, q2 & 0xFFFFF, c8, j0 + 8  < m);
                uint4 x3 = gz(entB, q3 & 0xFFFFF, c8, j0 + 12 < m);
                float4 wa0 = w4[(q0 >> 20) * 16 + (c8 << 1)];
                float4 wb0 = w4[(q0 >> 20) * 16 + (c8 << 1) + 1];
                float4 wa1 = w4[(q1 >> 20) * 16 + (c8 << 1)];
                float4 wb1 = w4[(q1 >> 20) * 16 + (c8 << 1) + 1];
                float4 wa2 = w4[(q2 >> 20) * 16 + (c8 << 1)];
                float4 wb2 = w4[(q2 >> 20) * 16 + (c8 << 1) + 1];
                float4 wa3 = w4[(q3 >> 20) * 16 + (c8 << 1)];
                float4 wb3 = w4[(q3 >> 20) * 16 + (c8 << 1) + 1];
                acc_edge(acc, x0, wa0, wb0);
                acc_edge(acc, x1, wa1, wb1);
                acc_edge(acc, x2, wa2, wb2);
                acc_edge(acc, x3, wa3, wb3);
            }
        }
        #pragma unroll
        for (int j = 0; j < 8; ++j) {            // combine 4 groups (within half)
            acc[j] += __shfl_xor(acc[j], 8, 64);
            acc[j] += __shfl_xor(acc[j], 16, 64);
        }
        float s = 0.0f;
        #pragma unroll
        for (int j = 0; j < 8; ++j) s += acc[j] * acc[j];
        s += __shfl_xor(s, 1, 64);
        s += __shfl_xor(s, 2, 64);
        s += __shfl_xor(s, 4, 64);
        float inv = 1.0f / fmaxf(sqrtf(s), 1e-12f);
        if (g == 0) {
            float y0 = acc[0] * inv, y1 = acc[1] * inv, y2 = acc[2] * inv, y3 = acc[3] * inv;
            float y4 = acc[4] * inv, y5 = acc[5] * inv, y6 = acc[6] * inv, y7 = acc[7] * inv;
            int qi = row * 16 + (c8 << 1);
            if (HOP0) {
                uint4 pk;
                pk.x = pack_bf16x2(y0, y1); pk.y = pack_bf16x2(y2, y3);
                pk.z = pack_bf16x2(y4, y5); pk.w = pack_bf16x2(y6, y7);
                nt_st4u(&((uint4*)AeB_out)[row * 8 + c8], pk);
                float4 b0 = nt_ld4f(&((const float4*)ent_base)[qi]);
                float4 b1 = nt_ld4f(&((const float4*)ent_base)[qi + 1]);
                nt_st4f(&((float4*)ent_res)[qi],     make_float4(b0.x + y0, b0.y + y1, b0.z + y2, b0.w + y3));
                nt_st4f(&((float4*)ent_res)[qi + 1], make_float4(b1.x + y4, b1.y + y5, b1.z + y6, b1.w + y7));
            } else {
                float4 r0 = nt_ld4f(&((const float4*)ent_res)[qi]);
                float4 r1 = nt_ld4f(&((const float4*)ent_res)[qi + 1]);
                nt_st4f(&((float4*)ent_res)[qi],     make_float4(r0.x + y0, r0.y + y1, r0.z + y2, r0.w + y3));
                nt_st4f(&((float4*)ent_res)[qi + 1], make_float4(r1.x + y4, r1.y + y5, r1.z + y6, r1.w + y7));
            }
        }
    } else {
        int row = (blockIdx.x - ENT_BLK8) * 8 + ((threadIdx.x >> 6) << 1) + h;
        int qi  = row * 16 + (c8 << 1);
        float4 u0 = nt_ld4f(&((const float4*)usr_in)[qi]);    // prefetch; used post-loop
        float4 u1 = nt_ld4f(&((const float4*)usr_in)[qi + 1]);
        int lo = offU[row], hi = offU[row + 1];
        for (int k0 = lo; k0 < hi; k0 += 32) {
            int m = min(32, hi - k0);
            int sidx = min(k0 + l5, NNZ - 1);
            int   cl = nt_ldi(&ucol[sidx]);
            float vl = nt_ldf(&uval[sidx]);
            for (int jj = 0; jj < m; jj += 16) {
                int j0 = jj + g;
                int   c0 = __shfl(cl, j0,      32);
                int   c1 = __shfl(cl, j0 + 4,  32);
                int   c2 = __shfl(cl, j0 + 8,  32);
                int   c3 = __shfl(cl, j0 + 12, 32);
                float v0 = __shfl(vl, j0,      32);
                float v1 = __shfl(vl, j0 + 4,  32);
                float v2 = __shfl(vl, j0 + 8,  32);
                float v3 = __shfl(vl, j0 + 12, 32);
                uint4 x0 = gz(entB, c0, c8, j0      < m);
                uint4 x1 = gz(entB, c1, c8, j0 + 4  < m);
                uint4 x2 = gz(entB, c2, c8, j0 + 8  < m);
                uint4 x3 = gz(entB, c3, c8, j0 + 12 < m);
                acc_user(acc, x0, v0);
                acc_user(acc, x1, v1);
                acc_user(acc, x2, v2);
                acc_user(acc, x3, v3);
            }
        }
        #pragma unroll
        for (int j = 0; j < 8; ++j) {
            acc[j] += __shfl_xor(acc[j], 8, 64);
            acc[j] += __shfl_xor(acc[j], 16, 64);
        }
        // softmax(u @ latent^T) @ dw — computed after the gather loop so the
        // usr_in loads prefetch under it.
        float d[N_FACTORS];
        #pragma unroll
        for (int f = 0; f < N_FACTORS; ++f) {
            float4 l0 = ((const float4*)latent)[f * 16 + (c8 << 1)];
            float4 l1 = ((const float4*)latent)[f * 16 + (c8 << 1) + 1];
            d[f] = u0.x * l0.x + u0.y * l0.y + u0.z * l0.z + u0.w * l0.w
                 + u1.x * l1.x + u1.y * l1.y + u1.z * l1.z + u1.w * l1.w;
            d[f] += __shfl_xor(d[f], 1, 64);
            d[f] += __shfl_xor(d[f], 2, 64);
            d[f] += __shfl_xor(d[f], 4, 64);
        }
        float mx = fmaxf(fmaxf(d[0], d[1]), fmaxf(d[2], d[3]));
        float ex0 = expf(d[0] - mx), ex1 = expf(d[1] - mx);
        float ex2 = expf(d[2] - mx), ex3 = expf(d[3] - mx);
        float sinv = 1.0f / (ex0 + ex1 + ex2 + ex3);
        float mix[8] = {0.f, 0.f, 0.f, 0.f, 0.f, 0.f, 0.f, 0.f};
        {
            float exf[N_FACTORS] = {ex0, ex1, ex2, ex3};
            #pragma unroll
            for (int f = 0; f < N_FACTORS; ++f) {
                float4 w0 = ((const float4*)dw)[f * 16 + (c8 << 1)];
                float4 w1 = ((const float4*)dw)[f * 16 + (c8 << 1) + 1];
                float ef = exf[f];
                mix[0] += ef * w0.x; mix[1] += ef * w0.y;
                mix[2] += ef * w0.z; mix[3] += ef * w0.w;
                mix[4] += ef * w1.x; mix[5] += ef * w1.y;
                mix[6] += ef * w1.z; mix[7] += ef * w1.w;
            }
            #pragma unroll
            for (int j = 0; j < 8; ++j) mix[j] *= sinv;
        }
        float un[8];
        #pragma unroll
        for (int j = 0; j < 8; ++j) un[j] = acc[j] * (1.0f + mix[j]);
        float s = 0.0f;
        #pragma unroll
        for (int j = 0; j < 8; ++j) s += un[j] * un[j];
        s += __shfl_xor(s, 1, 64);
        s += __shfl_xor(s, 2, 64);
        s += __shfl_xor(s, 4, 64);
        float inv = 1.0f / fmaxf(sqrtf(s), 1e-12f);
        if (g == 0) {
            float y0 = un[0] * inv, y1 = un[1] * inv, y2 = un[2] * inv, y3 = un[3] * inv;
            float y4 = un[4] * inv, y5 = un[5] * inv, y6 = un[6] * inv, y7 = un[7] * inv;
            if (HOP0) {
                // Write only Au (= y0). usr_res deferred to hop1:
                // final = usr_base + Au + y1 (bit-identical order).
                nt_st4f(&((float4*)Au_out)[qi],     make_float4(y0, y1, y2, y3));
                nt_st4f(&((float4*)Au_out)[qi + 1], make_float4(y4, y5, y6, y7));
            } else {
                // u0/u1 hold this row's Au (loaded as usr_in above).
                float4 b0 = nt_ld4f(&((const float4*)usr_base)[qi]);
                float4 b1 = nt_ld4f(&((const float4*)usr_base)[qi + 1]);
                nt_st4f(&((float4*)usr_res)[qi],
                        make_float4((b0.x + u0.x) + y0, (b0.y + u0.y) + y1,
                                    (b0.z + u0.z) + y2, (b0.w + u0.w) + y3));
                nt_st4f(&((float4*)usr_res)[qi + 1],
                        make_float4((b1.x + u1.x) + y4, (b1.y + u1.y) + y5,
                                    (b1.z + u1.z) + y6, (b1.w + u1.w) + y7));
            }
        }
    }
}

// ---------------------------------------------------------------------------
// Block 0: disen_weight = softmax(att,-1) @ weight (4x8 @ 8x64).
// Block 1: distance-correlation, one wave per factor pair.
__global__ __launch_bounds__(384)
void discor_kernel(const float* __restrict__ att,
                   const float* __restrict__ weight,
                   float* __restrict__ dw,
                   float* __restrict__ cor_out) {
    __shared__ float part[6];
    if (blockIdx.x == 0) {
        if (threadIdx.x < 256) {
            int f = threadIdx.x >> 6;
            int c = threadIdx.x & 63;
            float m = -1e30f;
            #pragma unroll
            for (int j = 0; j < N_RELM1; ++j) m = fmaxf(m, att[f * N_RELM1 + j]);
            float s = 0.0f, w[N_RELM1];
            #pragma unroll
            for (int j = 0; j < N_RELM1; ++j) { w[j] = expf(att[f * N_RELM1 + j] - m); s += w[j]; }
            float acc = 0.0f;
            #pragma unroll
            for (int j = 0; j < N_RELM1; ++j) acc += w[j] * weight[j * CH + c];
            dw[f * CH + c] = acc / s;
        }
    } else {
        int w    = threadIdx.x >> 6;   // 0..5 = pair index
        int lane = threadIdx.x & 63;
        const int pi[6] = {0, 0, 0, 1, 1, 2};
        const int pj[6] = {1, 2, 3, 2, 3, 3};
        int r = lane >> 3, c = lane & 7;
        const float* t1 = att + pi[w] * N_RELM1;
        const float* t2 = att + pj[w] * N_RELM1;
        float a  = sqrtf(fmaxf(t1[r] * t1[r] - 2.0f * t1[r] * t1[c] + t1[c] * t1[c], 0.0f) + 1e-8f);
        float bb = sqrtf(fmaxf(t2[r] * t2[r] - 2.0f * t2[r] * t2[c] + t2[c] * t2[c], 0.0f) + 1e-8f);
        float rsA = a, rsB = bb;
        #pragma unroll
        for (int o = 1; o < 8; o <<= 1) { rsA += __shfl_xor(rsA, o, 64); rsB += __shfl_xor(rsB, o, 64); }
        float csA = a, csB = bb;
        #pragma unroll
        for (int o = 8; o < 64; o <<= 1) { csA += __shfl_xor(csA, o, 64); csB += __shfl_xor(csB, o, 64); }
        float totA = rsA, totB = rsB;
        #pragma unroll
        for (int o = 8; o < 64; o <<= 1) { totA += __shfl_xor(totA, o, 64); totB += __shfl_xor(totB, o, 64); }
        float A = a  - csA * 0.125f - rsA * 0.125f + totA * (1.0f / 64.0f);
        float B = bb - csB * 0.125f - rsB * 0.125f + totB * (1.0f / 64.0f);
        float sAB = A * B, sAA = A * A, sBB = B * B;
        #pragma unroll
        for (int o = 1; o < 64; o <<= 1) {
            sAB += __shfl_xor(sAB, o, 64);
            sAA += __shfl_xor(sAA, o, 64);
            sBB += __shfl_xor(sBB, o, 64);
        }
        if (lane == 0) {
            float dAB = sqrtf(fmaxf(sAB * (1.0f / 64.0f), 0.0f) + 1e-8f);
            float dAA = sqrtf(fmaxf(sAA * (1.0f / 64.0f), 0.0f) + 1e-8f);
            float dBB = sqrtf(fmaxf(sBB * (1.0f / 64.0f), 0.0f) + 1e-8f);
            part[w] = dAB / sqrtf(dAA * dBB + 1e-8f);
        }
        __syncthreads();
        if (threadIdx.x == 0) {
            float s = 0.0f;
            for (int q = 0; q < 6; ++q) s += part[q];
            cor_out[0] = s;
        }
    }
}

// ---------------------------------------------------------------------------
extern "C" void kernel_launch(void* const* d_in, const int* in_sizes, int n_in,
                              void* d_out, int out_size, void* d_ws, size_t ws_size,
                              hipStream_t stream) {
    const float* user_emb   = (const float*)d_in[0];
    const float* entity_emb = (const float*)d_in[1];
    const float* latent     = (const float*)d_in[2];
    const float* weight     = (const float*)d_in[3];
    const float* att        = (const float*)d_in[4];
    const float* ivals      = (const float*)d_in[5];
    const int*   head       = (const int*)d_in[6];
    const int*   tail       = (const int*)d_in[7];
    const int*   etype      = (const int*)d_in[8];
    const int*   irows      = (const int*)d_in[9];
    const int*   icols      = (const int*)d_in[10];

    float* out     = (float*)d_out;
    float* ent_res = out;
    float* usr_res = out + (size_t)N_ENTITIES * CH;
    float* cor_out = out + (size_t)N_ENTITIES * CH + (size_t)N_USERS * CH;

    const size_t ENT_ELEMS = (size_t)N_ENTITIES * CH;   // 6.4M
    const size_t USR_ELEMS = (size_t)N_USERS * CH;      // 3.2M
    const int    ENT_PAIRS = (int)(ENT_ELEMS / 2);      // 3.2M u32

    // Workspace carve-up (~52 MB).
    // Region R: [entB | AeB] (25.6 MB) — aliased by the CSR staging arrays
    // (21.6 MB), which are dead before to_bf16/hop0 write entB/AeB.
    float* ws   = (float*)d_ws;
    u32*   entB = (u32*)ws;                         // 3.2M u32 (12.8 MB)
    u32*   AeB  = entB + ENT_PAIRS;                 // 3.2M u32 (12.8 MB)
    float* Au   = (float*)(AeB + ENT_PAIRS);        // 3.2M f32 (12.8 MB)
    float* dw   = Au + USR_ELEMS;                   // 4x64
    int*   offE = (int*)(dw + N_FACTORS * CH);      // 100001
    int*   offU = offE + N_ENTITIES + 1;            // 50001
    int*   elst = offU + N_USERS + 1;               // 1.5M packed
    int*   ucol = elst + N_EDGES;                   // 800K
    float* uval = (float*)(ucol + NNZ);             // 800K
    int*   H    = (int*)(uval + NNZ);               // NBKT*NBLK = 164947
    int*   T    = H + NBKT * NBLK;                  // 587
    int*   Bb   = T + NBKT;                         // 588
    // Staging aliased on R: 1.5M int2 + 800K int2 + 800K f32 = 21.6 MB < 25.6 MB
    int2*  stageE  = (int2*)entB;
    int2*  stageU  = ((int2*)entB) + N_EDGES;
    float* stageUv = (float*)(stageU + NNZ);

    discor_kernel<<<2, 384, 0, stream>>>(att, weight, dw, cor_out);

    // ---- Build CSR (no global atomics, no memsets) ----
    count_coarse<<<NBLK, 256, 0, stream>>>(head, irows, H);
    scan_hcols<<<NBKT, 64, 0, stream>>>(H, T);
    scan_buckets<<<1, 1024, 0, stream>>>(T, Bb);
    scatter_stage<<<NBLK, 256, 0, stream>>>(head, tail, etype, irows, icols, ivals,
                                            H, Bb, stageE, stageU, stageUv);
    bin_fill<<<NBKT, 256, 0, stream>>>(Bb, stageE, stageU, stageUv,
                                       offE, offU, elst, ucol, uval);

    // ---- Convert gather table to bf16 (staging now dead) ----
    to_bf16<<<(ENT_PAIRS + 255) / 256, 256, 0, stream>>>(entity_emb, entB, ENT_PAIRS);

    // ---- Hop 0 (gathers entB; writes AeB bf16 + Au fp32 + ent residual) ----
    hop_pass<true><<<ENT_BLK8 + USR_BLK8, 256, 0, stream>>>(
        entB, user_emb, weight, latent, dw,
        offE, elst, offU, ucol, uval,
        AeB, Au, ent_res, usr_res, entity_emb, user_emb);

    // ---- Hop 1 (gathers AeB; finishes residuals; usr uses base+Au+y1) ----
    hop_pass<false><<<ENT_BLK8 + USR_BLK8, 256, 0, stream>>>(
        AeB, Au, weight, latent, dw,
        offE, elst, offU, ucol, uval,
        nullptr, nullptr, ent_res, usr_res, entity_emb, user_emb);
}

// Round 9
// 347.861 us; speedup vs baseline: 1.1517x; 1.0390x over previous
//
#include <hip/hip_runtime.h>
#include <math.h>

// Problem constants (match reference)
constexpr int CH         = 64;
constexpr int N_USERS    = 50000;
constexpr int N_ENTITIES = 100000;
constexpr int N_FACTORS  = 4;
constexpr int N_RELM1    = 8;     // N_REL - 1
constexpr int N_EDGES    = 1500000;
constexpr int NNZ        = 800000;

constexpr int NBE        = (N_ENTITIES + 255) / 256;  // 391 coarse buckets (E)
constexpr int NBU        = (N_USERS + 255) / 256;     // 196 coarse buckets (U)
constexpr int NBKT       = NBE + NBU;                 // 587
constexpr int TOTAL      = N_EDGES + NNZ;             // 2.3M items
constexpr int IPB        = 2048;                      // items per count/stage block
constexpr int NBLK       = (TOTAL + IPB - 1) / IPB;   // 1124 (4.4 blocks/CU)
constexpr int ENT_BLK8   = N_ENTITIES / 8;            // 12500 (exact) — 8 rows/block
constexpr int USR_BLK8   = N_USERS / 8;               // 6250 (exact)

typedef unsigned int u32;
typedef float __attribute__((ext_vector_type(4))) f32x4;
typedef unsigned int __attribute__((ext_vector_type(4))) u32x4;

// ---------------------------------------------------------------------------
__device__ __forceinline__ u32 pack_bf16x2(float a, float b) {
    u32 ua = __float_as_uint(a), ub = __float_as_uint(b);
    u32 ra = (ua + 0x7FFFu + ((ua >> 16) & 1u)) >> 16;
    u32 rb = (ub + 0x7FFFu + ((ub >> 16) & 1u)) >> 16;
    return ra | (rb << 16);
}
__device__ __forceinline__ float bf_lo(u32 v) { return __uint_as_float(v << 16); }
__device__ __forceinline__ float bf_hi(u32 v) { return __uint_as_float(v & 0xFFFF0000u); }

// Non-temporal helpers: one-shot streams must NOT allocate in L2/L3 — the
// random-gather table needs that capacity. A/B evidence: R4/R8 (all-nt, occ
// 47%) = 81-82 µs/hop @175 MB; R5/R7 (occ 75%) = 92-97 µs @315 MB.
__device__ __forceinline__ float4 nt_ld4f(const float4* p) {
    f32x4 v = __builtin_nontemporal_load((const f32x4*)p);
    return make_float4(v.x, v.y, v.z, v.w);
}
__device__ __forceinline__ void nt_st4f(float4* p, float4 v) {
    f32x4 t; t.x = v.x; t.y = v.y; t.z = v.z; t.w = v.w;
    __builtin_nontemporal_store(t, (f32x4*)p);
}
__device__ __forceinline__ int   nt_ldi(const int* p)   { return __builtin_nontemporal_load(p); }
__device__ __forceinline__ float nt_ldf(const float* p) { return __builtin_nontemporal_load(p); }

// Exec-masked 16B row-slice gather: returns 0 when invalid (no request issued).
__device__ __forceinline__ uint4 gz(const u32* __restrict__ t, int r, int c8, bool v) {
    uint4 x = make_uint4(0u, 0u, 0u, 0u);
    if (v) x = ((const uint4*)t)[r * 8 + c8];
    return x;
}

__device__ __forceinline__ int coarse_bucket(int i, const int* __restrict__ head,
                                             const int* __restrict__ irows) {
    return (i < N_EDGES) ? (head[i] >> 8) : (NBE + (irows[i - N_EDGES] >> 8));
}

// ---------------------------------------------------------------------------
// A: per-block coarse-bucket histogram -> H[bucket * NBLK + block].
__global__ __launch_bounds__(256)
void count_coarse(const int* __restrict__ head, const int* __restrict__ irows,
                  int* __restrict__ H) {
    __shared__ int hist[NBKT];
    for (int j = threadIdx.x; j < NBKT; j += 256) hist[j] = 0;
    __syncthreads();
    int start = blockIdx.x * IPB;
    int end   = min(start + IPB, TOTAL);
    for (int i = start + threadIdx.x; i < end; i += 256)
        atomicAdd(&hist[coarse_bucket(i, head, irows)], 1);
    __syncthreads();
    for (int j = threadIdx.x; j < NBKT; j += 256)
        H[j * NBLK + blockIdx.x] = hist[j];
}

// B1: one wave per bucket — exclusive scan of H[bucket][0..NBLK), total -> T.
__global__ __launch_bounds__(64)
void scan_hcols(int* __restrict__ H, int* __restrict__ T) {
    int b = blockIdx.x, lane = threadIdx.x;
    int carry = 0;
    for (int c = 0; c < (NBLK + 63) / 64; ++c) {
        int idx = c * 64 + lane;
        int v = (idx < NBLK) ? H[b * NBLK + idx] : 0;
        int incl = v;
        #pragma unroll
        for (int d = 1; d < 64; d <<= 1) {
            int u = __shfl_up(incl, d, 64);
            if (lane >= d) incl += u;
        }
        if (idx < NBLK) H[b * NBLK + idx] = carry + incl - v;
        carry += __shfl(incl, 63, 64);
    }
    if (lane == 0) T[b] = carry;
}

// B2: single block — exclusive scan of T -> Bb, sentinel Bb[NBKT].
__global__ __launch_bounds__(1024)
void scan_buckets(const int* __restrict__ T, int* __restrict__ Bb) {
    __shared__ int lds[1024];
    int t = threadIdx.x;
    int v = (t < NBKT) ? T[t] : 0;
    lds[t] = v;
    __syncthreads();
    for (int d = 1; d < 1024; d <<= 1) {
        int u = (t >= d) ? lds[t - d] : 0;
        __syncthreads();
        lds[t] += u;
        __syncthreads();
    }
    if (t < NBKT) Bb[t] = lds[t] - v;
    if (t == NBKT - 1) Bb[NBKT] = lds[t];
}

// ---------------------------------------------------------------------------
// C: partition into coarse buckets; per-block ranges pre-reserved, LDS atomics.
// Staging records are COMPACT u32:
//   E: tail(0-16) | rel(17-19) | keylow(20-27)
//   U: icol(0-16) | keylow(17-24)           (+ separate f32 value)
__global__ __launch_bounds__(256)
void scatter_stage(const int* __restrict__ head, const int* __restrict__ tail,
                   const int* __restrict__ etype,
                   const int* __restrict__ irows, const int* __restrict__ icols,
                   const float* __restrict__ ivals,
                   const int* __restrict__ H, const int* __restrict__ Bb,
                   u32* __restrict__ stageE, u32* __restrict__ stageU,
                   float* __restrict__ stageUv) {
    __shared__ int cur[NBKT];
    for (int j = threadIdx.x; j < NBKT; j += 256)
        cur[j] = Bb[j] + H[j * NBLK + blockIdx.x];
    __syncthreads();
    int start = blockIdx.x * IPB;
    int end   = min(start + IPB, TOTAL);
    for (int i = start + threadIdx.x; i < end; i += 256) {
        if (i < N_EDGES) {
            int k   = head[i];
            u32 rec = (u32)tail[i] | ((u32)(etype[i] - 1) << 17) | ((u32)(k & 255) << 20);
            int pos = atomicAdd(&cur[k >> 8], 1);
            stageE[pos] = rec;
        } else {
            int ii  = i - N_EDGES;
            int k   = irows[ii];
            int pos = atomicAdd(&cur[NBE + (k >> 8)], 1) - N_EDGES;
            stageU[pos]  = (u32)icols[ii] | ((u32)(k & 255) << 17);
            stageUv[pos] = ivals[ii];
        }
    }
}

// ---------------------------------------------------------------------------
// D: one block per bucket; LDS key-hist + scan -> CSR offsets, scatter to CSR.
__global__ __launch_bounds__(256)
void bin_fill(const int* __restrict__ Bb,
              const u32* __restrict__ stageE, const u32* __restrict__ stageU,
              const float* __restrict__ stageUv,
              int* __restrict__ offE, int* __restrict__ offU,
              int* __restrict__ elst, int* __restrict__ ucol,
              float* __restrict__ uval) {
    __shared__ int khist[256];
    __shared__ int cur[256];
    int b = blockIdx.x, t = threadIdx.x;
    khist[t] = 0;
    __syncthreads();
    if (b < NBE) {
        int lo = Bb[b], hi = Bb[b + 1];
        for (int i = lo + t; i < hi; i += 256)
            atomicAdd(&khist[(stageE[i] >> 20) & 255], 1);
        __syncthreads();
        int v = khist[t];
        for (int d = 1; d < 256; d <<= 1) {
            int u = (t >= d) ? khist[t - d] : 0;
            __syncthreads();
            khist[t] += u;
            __syncthreads();
        }
        int excl = lo + khist[t] - v;
        int key  = b * 256 + t;
        if (key < N_ENTITIES) offE[key] = excl;
        cur[t] = excl;
        __syncthreads();
        for (int i = lo + t; i < hi; i += 256) {
            u32 s = stageE[i];
            int p = atomicAdd(&cur[(s >> 20) & 255], 1);
            elst[p] = (int)(s & 0xFFFFFu);      // tail | rel<<17
        }
        if (b == 0 && t == 0) offE[N_ENTITIES] = N_EDGES;
    } else {
        int lo = Bb[b] - N_EDGES, hi = Bb[b + 1] - N_EDGES;
        for (int i = lo + t; i < hi; i += 256)
            atomicAdd(&khist[(stageU[i] >> 17) & 255], 1);
        __syncthreads();
        int v = khist[t];
        for (int d = 1; d < 256; d <<= 1) {
            int u = (t >= d) ? khist[t - d] : 0;
            __syncthreads();
            khist[t] += u;
            __syncthreads();
        }
        int excl = lo + khist[t] - v;
        int key  = (b - NBE) * 256 + t;
        if (key < N_USERS) offU[key] = excl;
        cur[t] = excl;
        __syncthreads();
        for (int i = lo + t; i < hi; i += 256) {
            u32 s = stageU[i];
            float vv = stageUv[i];
            int p = atomicAdd(&cur[(s >> 17) & 255], 1);
            ucol[p] = (int)(s & 0x1FFFFu);
            uval[p] = vv;
        }
        if (b == NBE && t == 0) offU[N_USERS] = NNZ;
    }
}

// ---------------------------------------------------------------------------
// Convert fp32 table -> packed bf16x2 (u32 per channel pair).
__global__ __launch_bounds__(256)
void to_bf16(const float* __restrict__ src, u32* __restrict__ dst, int n2) {
    int i = blockIdx.x * 256 + threadIdx.x;
    if (i < n2) {
        float2 f = ((const float2*)src)[i];
        dst[i] = pack_bf16x2(f.x, f.y);
    }
}

// ---------------------------------------------------------------------------
// Fused per-hop pass, bf16 gather table.
// Wave = 2 rows (h = lane>>5). Within a half: g = (lane>>3)&3 (4 gather groups
// of 8), c8 = lane&7 (channel octet -> one uint4 = 128b row slice per gather).
// Per 32-edge chunk: ONE coalesced 32-lane index load, then __shfl(p,j,32)
// register broadcasts feed the gathers — no memory op on the index path.
// Cache policy (R4/R8 proven): all one-shot streams nt; table gathers cached.
// AeB (hop1's gather table) stored CACHED so hop1 starts L2/L3-warm.
// NO min-waves clause — LB(256,8) raised occupancy to 75% and REGRESSED
// (R7: +140 MB L2-miss traffic): the hop is L2-miss-path bound.
// elst payload: tail(0-16) | rel(17-19).
__device__ __forceinline__ void acc_edge(float* acc, uint4 xv, float4 wa, float4 wb) {
    acc[0] += bf_lo(xv.x) * wa.x; acc[1] += bf_hi(xv.x) * wa.y;
    acc[2] += bf_lo(xv.y) * wa.z; acc[3] += bf_hi(xv.y) * wa.w;
    acc[4] += bf_lo(xv.z) * wb.x; acc[5] += bf_hi(xv.z) * wb.y;
    acc[6] += bf_lo(xv.w) * wb.z; acc[7] += bf_hi(xv.w) * wb.w;
}
__device__ __forceinline__ void acc_user(float* acc, uint4 xv, float vv) {
    acc[0] += vv * bf_lo(xv.x); acc[1] += vv * bf_hi(xv.x);
    acc[2] += vv * bf_lo(xv.y); acc[3] += vv * bf_hi(xv.y);
    acc[4] += vv * bf_lo(xv.z); acc[5] += vv * bf_hi(xv.z);
    acc[6] += vv * bf_lo(xv.w); acc[7] += vv * bf_hi(xv.w);
}

template <bool HOP0>
__global__ __launch_bounds__(256)
void hop_pass(const u32* __restrict__ entB,       // bf16x2 entity table (gathered)
              const float* __restrict__ usr_in,   // fp32 user emb (dense)
              const float* __restrict__ weight, const float* __restrict__ latent,
              const float* __restrict__ dw,
              const int* __restrict__ offE, const int* __restrict__ elst,
              const int* __restrict__ offU, const int* __restrict__ ucol,
              const float* __restrict__ uval,
              u32* __restrict__ AeB_out,          // bf16x2 entity out (hop0)
              float* __restrict__ Au_out,         // fp32 user out (hop0)
              float* __restrict__ ent_res, float* __restrict__ usr_res,
              const float* __restrict__ ent_base, const float* __restrict__ usr_base) {
    __shared__ float4 w4[N_RELM1 * 16];           // weight as float4 rows (2KB)
    int lane = threadIdx.x & 63;
    int h    = lane >> 5;          // row of the pair
    int g    = (lane >> 3) & 3;    // gather group within half
    int c8   = lane & 7;           // channel octet
    int l5   = lane & 31;
    float acc[8] = {0.f, 0.f, 0.f, 0.f, 0.f, 0.f, 0.f, 0.f};

    if ((int)blockIdx.x < ENT_BLK8) {
        if (threadIdx.x < N_RELM1 * 16)
            w4[threadIdx.x] = ((const float4*)weight)[threadIdx.x];
        __syncthreads();
        int row = blockIdx.x * 8 + ((threadIdx.x >> 6) << 1) + h;
        int lo = offE[row], hi = offE[row + 1];
        for (int k0 = lo; k0 < hi; k0 += 32) {
            int m = min(32, hi - k0);                       // uniform per half
            int p = nt_ldi(&elst[min(k0 + l5, N_EDGES - 1)]);
            for (int jj = 0; jj < m; jj += 16) {
                int j0 = jj + g;
                int q0 = __shfl(p, j0,      32);
                int q1 = __shfl(p, j0 + 4,  32);
                int q2 = __shfl(p, j0 + 8,  32);
                int q3 = __shfl(p, j0 + 12, 32);
                uint4 x0 = gz(entB, q0 & 0x1FFFF, c8, j0      < m);
                uint4 x1 = gz(entB, q1 & 0x1FFFF, c8, j0 + 4  < m);
                uint4 x2 = gz(entB, q2 & 0x1FFFF, c8, j0 + 8  < m);
                uint4 x3 = gz(entB, q3 & 0x1FFFF, c8, j0 + 12 < m);
                float4 wa0 = w4[(q0 >> 17) * 16 + (c8 << 1)];
                float4 wb0 = w4[(q0 >> 17) * 16 + (c8 << 1) + 1];
                float4 wa1 = w4[(q1 >> 17) * 16 + (c8 << 1)];
                float4 wb1 = w4[(q1 >> 17) * 16 + (c8 << 1) + 1];
                float4 wa2 = w4[(q2 >> 17) * 16 + (c8 << 1)];
                float4 wb2 = w4[(q2 >> 17) * 16 + (c8 << 1) + 1];
                float4 wa3 = w4[(q3 >> 17) * 16 + (c8 << 1)];
                float4 wb3 = w4[(q3 >> 17) * 16 + (c8 << 1) + 1];
                acc_edge(acc, x0, wa0, wb0);
                acc_edge(acc, x1, wa1, wb1);
                acc_edge(acc, x2, wa2, wb2);
                acc_edge(acc, x3, wa3, wb3);
            }
        }
        #pragma unroll
        for (int j = 0; j < 8; ++j) {            // combine 4 groups (within half)
            acc[j] += __shfl_xor(acc[j], 8, 64);
            acc[j] += __shfl_xor(acc[j], 16, 64);
        }
        float s = 0.0f;
        #pragma unroll
        for (int j = 0; j < 8; ++j) s += acc[j] * acc[j];
        s += __shfl_xor(s, 1, 64);
        s += __shfl_xor(s, 2, 64);
        s += __shfl_xor(s, 4, 64);
        float inv = 1.0f / fmaxf(sqrtf(s), 1e-12f);
        if (g == 0) {
            float y0 = acc[0] * inv, y1 = acc[1] * inv, y2 = acc[2] * inv, y3 = acc[3] * inv;
            float y4 = acc[4] * inv, y5 = acc[5] * inv, y6 = acc[6] * inv, y7 = acc[7] * inv;
            int qi = row * 16 + (c8 << 1);
            if (HOP0) {
                uint4 pk;
                pk.x = pack_bf16x2(y0, y1); pk.y = pack_bf16x2(y2, y3);
                pk.z = pack_bf16x2(y4, y5); pk.w = pack_bf16x2(y6, y7);
                ((uint4*)AeB_out)[row * 8 + c8] = pk;   // hop1's gather table: cached
                float4 b0 = nt_ld4f(&((const float4*)ent_base)[qi]);
                float4 b1 = nt_ld4f(&((const float4*)ent_base)[qi + 1]);
                nt_st4f(&((float4*)ent_res)[qi],     make_float4(b0.x + y0, b0.y + y1, b0.z + y2, b0.w + y3));
                nt_st4f(&((float4*)ent_res)[qi + 1], make_float4(b1.x + y4, b1.y + y5, b1.z + y6, b1.w + y7));
            } else {
                float4 r0 = nt_ld4f(&((const float4*)ent_res)[qi]);
                float4 r1 = nt_ld4f(&((const float4*)ent_res)[qi + 1]);
                nt_st4f(&((float4*)ent_res)[qi],     make_float4(r0.x + y0, r0.y + y1, r0.z + y2, r0.w + y3));
                nt_st4f(&((float4*)ent_res)[qi + 1], make_float4(r1.x + y4, r1.y + y5, r1.z + y6, r1.w + y7));
            }
        }
    } else {
        int row = (blockIdx.x - ENT_BLK8) * 8 + ((threadIdx.x >> 6) << 1) + h;
        int qi  = row * 16 + (c8 << 1);
        float4 u0 = nt_ld4f(&((const float4*)usr_in)[qi]);    // prefetch; used post-loop
        float4 u1 = nt_ld4f(&((const float4*)usr_in)[qi + 1]);
        int lo = offU[row], hi = offU[row + 1];
        for (int k0 = lo; k0 < hi; k0 += 32) {
            int m = min(32, hi - k0);
            int sidx = min(k0 + l5, NNZ - 1);
            int   cl = nt_ldi(&ucol[sidx]);
            float vl = nt_ldf(&uval[sidx]);
            for (int jj = 0; jj < m; jj += 16) {
                int j0 = jj + g;
                int   c0 = __shfl(cl, j0,      32);
                int   c1 = __shfl(cl, j0 + 4,  32);
                int   c2 = __shfl(cl, j0 + 8,  32);
                int   c3 = __shfl(cl, j0 + 12, 32);
                float v0 = __shfl(vl, j0,      32);
                float v1 = __shfl(vl, j0 + 4,  32);
                float v2 = __shfl(vl, j0 + 8,  32);
                float v3 = __shfl(vl, j0 + 12, 32);
                uint4 x0 = gz(entB, c0, c8, j0      < m);
                uint4 x1 = gz(entB, c1, c8, j0 + 4  < m);
                uint4 x2 = gz(entB, c2, c8, j0 + 8  < m);
                uint4 x3 = gz(entB, c3, c8, j0 + 12 < m);
                acc_user(acc, x0, v0);
                acc_user(acc, x1, v1);
                acc_user(acc, x2, v2);
                acc_user(acc, x3, v3);
            }
        }
        #pragma unroll
        for (int j = 0; j < 8; ++j) {
            acc[j] += __shfl_xor(acc[j], 8, 64);
            acc[j] += __shfl_xor(acc[j], 16, 64);
        }
        // softmax(u @ latent^T) @ dw — computed after the gather loop so the
        // usr_in loads prefetch under it.
        float d[N_FACTORS];
        #pragma unroll
        for (int f = 0; f < N_FACTORS; ++f) {
            float4 l0 = ((const float4*)latent)[f * 16 + (c8 << 1)];
            float4 l1 = ((const float4*)latent)[f * 16 + (c8 << 1) + 1];
            d[f] = u0.x * l0.x + u0.y * l0.y + u0.z * l0.z + u0.w * l0.w
                 + u1.x * l1.x + u1.y * l1.y + u1.z * l1.z + u1.w * l1.w;
            d[f] += __shfl_xor(d[f], 1, 64);
            d[f] += __shfl_xor(d[f], 2, 64);
            d[f] += __shfl_xor(d[f], 4, 64);
        }
        float mx = fmaxf(fmaxf(d[0], d[1]), fmaxf(d[2], d[3]));
        float ex0 = expf(d[0] - mx), ex1 = expf(d[1] - mx);
        float ex2 = expf(d[2] - mx), ex3 = expf(d[3] - mx);
        float sinv = 1.0f / (ex0 + ex1 + ex2 + ex3);
        float mix[8] = {0.f, 0.f, 0.f, 0.f, 0.f, 0.f, 0.f, 0.f};
        {
            float exf[N_FACTORS] = {ex0, ex1, ex2, ex3};
            #pragma unroll
            for (int f = 0; f < N_FACTORS; ++f) {
                float4 w0 = ((const float4*)dw)[f * 16 + (c8 << 1)];
                float4 w1 = ((const float4*)dw)[f * 16 + (c8 << 1) + 1];
                float ef = exf[f];
                mix[0] += ef * w0.x; mix[1] += ef * w0.y;
                mix[2] += ef * w0.z; mix[3] += ef * w0.w;
                mix[4] += ef * w1.x; mix[5] += ef * w1.y;
                mix[6] += ef * w1.z; mix[7] += ef * w1.w;
            }
            #pragma unroll
            for (int j = 0; j < 8; ++j) mix[j] *= sinv;
        }
        float un[8];
        #pragma unroll
        for (int j = 0; j < 8; ++j) un[j] = acc[j] * (1.0f + mix[j]);
        float s = 0.0f;
        #pragma unroll
        for (int j = 0; j < 8; ++j) s += un[j] * un[j];
        s += __shfl_xor(s, 1, 64);
        s += __shfl_xor(s, 2, 64);
        s += __shfl_xor(s, 4, 64);
        float inv = 1.0f / fmaxf(sqrtf(s), 1e-12f);
        if (g == 0) {
            float y0 = un[0] * inv, y1 = un[1] * inv, y2 = un[2] * inv, y3 = un[3] * inv;
            float y4 = un[4] * inv, y5 = un[5] * inv, y6 = un[6] * inv, y7 = un[7] * inv;
            if (HOP0) {
                // Write only Au (= y0). usr_res deferred to hop1:
                // final = usr_base + Au + y1 (bit-identical order).
                nt_st4f(&((float4*)Au_out)[qi],     make_float4(y0, y1, y2, y3));
                nt_st4f(&((float4*)Au_out)[qi + 1], make_float4(y4, y5, y6, y7));
            } else {
                // u0/u1 hold this row's Au (loaded as usr_in above).
                float4 b0 = nt_ld4f(&((const float4*)usr_base)[qi]);
                float4 b1 = nt_ld4f(&((const float4*)usr_base)[qi + 1]);
                nt_st4f(&((float4*)usr_res)[qi],
                        make_float4((b0.x + u0.x) + y0, (b0.y + u0.y) + y1,
                                    (b0.z + u0.z) + y2, (b0.w + u0.w) + y3));
                nt_st4f(&((float4*)usr_res)[qi + 1],
                        make_float4((b1.x + u1.x) + y4, (b1.y + u1.y) + y5,
                                    (b1.z + u1.z) + y6, (b1.w + u1.w) + y7));
            }
        }
    }
}

// ---------------------------------------------------------------------------
// Block 0: disen_weight = softmax(att,-1) @ weight (4x8 @ 8x64).
// Block 1: distance-correlation, one wave per factor pair.
__global__ __launch_bounds__(384)
void discor_kernel(const float* __restrict__ att,
                   const float* __restrict__ weight,
                   float* __restrict__ dw,
                   float* __restrict__ cor_out) {
    __shared__ float part[6];
    if (blockIdx.x == 0) {
        if (threadIdx.x < 256) {
            int f = threadIdx.x >> 6;
            int c = threadIdx.x & 63;
            float m = -1e30f;
            #pragma unroll
            for (int j = 0; j < N_RELM1; ++j) m = fmaxf(m, att[f * N_RELM1 + j]);
            float s = 0.0f, w[N_RELM1];
            #pragma unroll
            for (int j = 0; j < N_RELM1; ++j) { w[j] = expf(att[f * N_RELM1 + j] - m); s += w[j]; }
            float acc = 0.0f;
            #pragma unroll
            for (int j = 0; j < N_RELM1; ++j) acc += w[j] * weight[j * CH + c];
            dw[f * CH + c] = acc / s;
        }
    } else {
        int w    = threadIdx.x >> 6;   // 0..5 = pair index
        int lane = threadIdx.x & 63;
        const int pi[6] = {0, 0, 0, 1, 1, 2};
        const int pj[6] = {1, 2, 3, 2, 3, 3};
        int r = lane >> 3, c = lane & 7;
        const float* t1 = att + pi[w] * N_RELM1;
        const float* t2 = att + pj[w] * N_RELM1;
        float a  = sqrtf(fmaxf(t1[r] * t1[r] - 2.0f * t1[r] * t1[c] + t1[c] * t1[c], 0.0f) + 1e-8f);
        float bb = sqrtf(fmaxf(t2[r] * t2[r] - 2.0f * t2[r] * t2[c] + t2[c] * t2[c], 0.0f) + 1e-8f);
        float rsA = a, rsB = bb;
        #pragma unroll
        for (int o = 1; o < 8; o <<= 1) { rsA += __shfl_xor(rsA, o, 64); rsB += __shfl_xor(rsB, o, 64); }
        float csA = a, csB = bb;
        #pragma unroll
        for (int o = 8; o < 64; o <<= 1) { csA += __shfl_xor(csA, o, 64); csB += __shfl_xor(csB, o, 64); }
        float totA = rsA, totB = rsB;
        #pragma unroll
        for (int o = 8; o < 64; o <<= 1) { totA += __shfl_xor(totA, o, 64); totB += __shfl_xor(totB, o, 64); }
        float A = a  - csA * 0.125f - rsA * 0.125f + totA * (1.0f / 64.0f);
        float B = bb - csB * 0.125f - rsB * 0.125f + totB * (1.0f / 64.0f);
        float sAB = A * B, sAA = A * A, sBB = B * B;
        #pragma unroll
        for (int o = 1; o < 64; o <<= 1) {
            sAB += __shfl_xor(sAB, o, 64);
            sAA += __shfl_xor(sAA, o, 64);
            sBB += __shfl_xor(sBB, o, 64);
        }
        if (lane == 0) {
            float dAB = sqrtf(fmaxf(sAB * (1.0f / 64.0f), 0.0f) + 1e-8f);
            float dAA = sqrtf(fmaxf(sAA * (1.0f / 64.0f), 0.0f) + 1e-8f);
            float dBB = sqrtf(fmaxf(sBB * (1.0f / 64.0f), 0.0f) + 1e-8f);
            part[w] = dAB / sqrtf(dAA * dBB + 1e-8f);
        }
        __syncthreads();
        if (threadIdx.x == 0) {
            float s = 0.0f;
            for (int q = 0; q < 6; ++q) s += part[q];
            cor_out[0] = s;
        }
    }
}

// ---------------------------------------------------------------------------
extern "C" void kernel_launch(void* const* d_in, const int* in_sizes, int n_in,
                              void* d_out, int out_size, void* d_ws, size_t ws_size,
                              hipStream_t stream) {
    const float* user_emb   = (const float*)d_in[0];
    const float* entity_emb = (const float*)d_in[1];
    const float* latent     = (const float*)d_in[2];
    const float* weight     = (const float*)d_in[3];
    const float* att        = (const float*)d_in[4];
    const float* ivals      = (const float*)d_in[5];
    const int*   head       = (const int*)d_in[6];
    const int*   tail       = (const int*)d_in[7];
    const int*   etype      = (const int*)d_in[8];
    const int*   irows      = (const int*)d_in[9];
    const int*   icols      = (const int*)d_in[10];

    float* out     = (float*)d_out;
    float* ent_res = out;
    float* usr_res = out + (size_t)N_ENTITIES * CH;
    float* cor_out = out + (size_t)N_ENTITIES * CH + (size_t)N_USERS * CH;

    const size_t ENT_ELEMS = (size_t)N_ENTITIES * CH;   // 6.4M
    const size_t USR_ELEMS = (size_t)N_USERS * CH;      // 3.2M
    const int    ENT_PAIRS = (int)(ENT_ELEMS / 2);      // 3.2M u32

    // Workspace carve-up (~51.5 MB).
    // Region R1 [entB | AeB] (25.6 MB): aliased by compact staging (12.4 MB),
    //   dead before to_bf16/hop0 write entB/AeB.
    // Region R2 [Au] (12.8 MB): aliased by H/T/Bb (2.65 MB), dead before
    //   hop0 writes Au.
    float* ws   = (float*)d_ws;
    u32*   entB = (u32*)ws;                         // 3.2M u32 (12.8 MB)
    u32*   AeB  = entB + ENT_PAIRS;                 // 3.2M u32 (12.8 MB)
    float* Au   = (float*)(AeB + ENT_PAIRS);        // 3.2M f32 (12.8 MB)
    float* dw   = Au + USR_ELEMS;                   // 4x64
    int*   offE = (int*)(dw + N_FACTORS * CH);      // 100001
    int*   offU = offE + N_ENTITIES + 1;            // 50001
    int*   elst = offU + N_USERS + 1;               // 1.5M packed
    int*   ucol = elst + N_EDGES;                   // 800K
    float* uval = (float*)(ucol + NNZ);             // 800K
    // H/T/Bb alias Au (dead before hop0):
    int*   H    = (int*)Au;                         // NBKT*NBLK = 659,788 ints
    int*   T    = H + NBKT * NBLK;                  // 587
    int*   Bb   = T + NBKT;                         // 588
    // Compact staging aliased on R1: 1.5M + 800K u32 + 800K f32 = 12.4 MB
    u32*   stageE  = entB;
    u32*   stageU  = entB + N_EDGES;
    float* stageUv = (float*)(stageU + NNZ);

    discor_kernel<<<2, 384, 0, stream>>>(att, weight, dw, cor_out);

    // ---- Build CSR (no global atomics, no memsets) ----
    count_coarse<<<NBLK, 256, 0, stream>>>(head, irows, H);
    scan_hcols<<<NBKT, 64, 0, stream>>>(H, T);
    scan_buckets<<<1, 1024, 0, stream>>>(T, Bb);
    scatter_stage<<<NBLK, 256, 0, stream>>>(head, tail, etype, irows, icols, ivals,
                                            H, Bb, stageE, stageU, stageUv);
    bin_fill<<<NBKT, 256, 0, stream>>>(Bb, stageE, stageU, stageUv,
                                       offE, offU, elst, ucol, uval);

    // ---- Convert gather table to bf16 (staging now dead) ----
    to_bf16<<<(ENT_PAIRS + 255) / 256, 256, 0, stream>>>(entity_emb, entB, ENT_PAIRS);

    // ---- Hop 0 (gathers entB; writes AeB bf16 + Au fp32 + ent residual) ----
    hop_pass<true><<<ENT_BLK8 + USR_BLK8, 256, 0, stream>>>(
        entB, user_emb, weight, latent, dw,
        offE, elst, offU, ucol, uval,
        AeB, Au, ent_res, usr_res, entity_emb, user_emb);

    // ---- Hop 1 (gathers AeB; finishes residuals; usr uses base+Au+y1) ----
    hop_pass<false><<<ENT_BLK8 + USR_BLK8, 256, 0, stream>>>(
        AeB, Au, weight, latent, dw,
        offE, elst, offU, ucol, uval,
        nullptr, nullptr, ent_res, usr_res, entity_emb, user_emb);
}